// Round 11
// baseline (371.413 us; speedup 1.0000x reference)
//
#include <hip/hip_runtime.h>

// ---------------------------------------------------------------------------
// GatheringLoss: phase-only FFT reconstruction -> dense score -> top-1 -> SSE
// queries: (8, 4096, 512) f32, items: (1024, 512) f32, out: (8, 4096) f32
// unit = irfft(exp(-1j*angle(rfft(q)))) == real(FFT(X/|X|))/N, X = FFT(q).
// Score GEMM on MFMA f16, exact 2-way split (3 products, lo*lo omitted;
// operands pre-scaled by 2^10 -> argmax invariant).
// A3/B3 fragment-major: a wave's MFMA fragment = one coalesced 1 KB load.
// fft_phase: direct-q two-for-one pack, XCD-remapped blocks (each XCD owns
// one batch -> q cache lines shared within one L2), single-LDS-buffer
// in-place Stockham (32 KB -> 4 blocks/CU).
// ---------------------------------------------------------------------------

#define NB 8
#define NS 4096
#define NF 512
#define NK 1024
#define NROWS (NB * NS)      // 32768
#define NKB 8                // n-chunks of 128

// FFT LDS swizzle (verified conflict-reducing for radix-16 Stockham).
#define SWZF(i) ((i) ^ (((i) >> 4) & 15))

typedef _Float16 half8 __attribute__((ext_vector_type(8)));
typedef float floatx4 __attribute__((ext_vector_type(4)));
struct H2 { _Float16 x, y; };   // (hi, lo)

__device__ __forceinline__ float2 cmulf(float2 a, float2 b) {
    return make_float2(a.x * b.x - a.y * b.y, a.x * b.y + a.y * b.x);
}

__device__ __forceinline__ float2 unitize(float2 v) {
    float m2 = v.x * v.x + v.y * v.y;
    if (m2 > 0.f) {
        float inv = 1.0f / sqrtf(m2);
        return make_float2(v.x * inv, v.y * inv);
    }
    return make_float2(1.f, 0.f);
}

__device__ __forceinline__ H2 split_h2(float v) {
    _Float16 h = (_Float16)v;
    float lo = v - (float)h;
    H2 r; r.x = h; r.y = (_Float16)lo; return r;
}

// o[k] = sum_n in[n] * (-i)^(n*k)
__device__ __forceinline__ void dft4(float2 a, float2 b, float2 c, float2 d,
                                     float2& o0, float2& o1, float2& o2, float2& o3) {
    float2 apc = make_float2(a.x + c.x, a.y + c.y);
    float2 amc = make_float2(a.x - c.x, a.y - c.y);
    float2 bpd = make_float2(b.x + d.x, b.y + d.y);
    float2 bmd = make_float2(b.x - d.x, b.y - d.y);
    o0 = make_float2(apc.x + bpd.x, apc.y + bpd.y);
    o1 = make_float2(amc.x + bmd.y, amc.y - bmd.x);   // amc - i*bmd
    o2 = make_float2(apc.x - bpd.x, apc.y - bpd.y);
    o3 = make_float2(amc.x - bmd.y, amc.y + bmd.x);   // amc + i*bmd
}

// ---------------------------------------------------------------------------
// Kernel 1: twiddle table W[k] = exp(-2*pi*i*k/4096), fp64-computed
// ---------------------------------------------------------------------------
__global__ void twiddle_init(float2* __restrict__ W) {
    int k = blockIdx.x * 256 + threadIdx.x;
    double ang = -2.0 * 3.14159265358979323846 * (double)k / 4096.0;
    W[k] = make_float2((float)cos(ang), (float)sin(ang));
}

// ---------------------------------------------------------------------------
// Radix-16 Stockham 4096-pt FFT, IN-PLACE in one LDS buffer: per stage,
// every thread reads its 16 inputs into registers, barrier, computes the
// DFT16, writes, barrier. 3 stages (s = 1, 16, 256), 256 threads.
// ---------------------------------------------------------------------------
__device__ __forceinline__ void fft4096_r16_ip(float2* buf,
                                               const float2* __restrict__ W,
                                               int t) {
    const float C1 = 0.92387953251128674f;   // cos(pi/8)
    const float S1 = 0.38268343236508978f;   // sin(pi/8)
    const float R2 = 0.70710678118654752f;
    const float2 w1 = make_float2(C1, -S1);
    const float2 w2 = make_float2(R2, -R2);
    const float2 w3 = make_float2(S1, -C1);
    const float2 w4 = make_float2(0.f, -1.f);
    const float2 w6 = make_float2(-R2, -R2);
    const float2 w9 = make_float2(-C1, S1);
#pragma unroll
    for (int st = 0; st < 3; ++st) {
        const int s = (st == 0) ? 1 : (st == 1) ? 16 : 256;
        __syncthreads();                 // prior writes visible
        float2 x[16];
#pragma unroll
        for (int j = 0; j < 16; ++j) x[j] = buf[SWZF(t + j * 256)];
        __syncthreads();                 // all reads done before overwrite
        float2 y[4][4];   // y[n0][k0]
#pragma unroll
        for (int n0 = 0; n0 < 4; ++n0)
            dft4(x[n0], x[4 + n0], x[8 + n0], x[12 + n0],
                 y[n0][0], y[n0][1], y[n0][2], y[n0][3]);
        y[1][1] = cmulf(w1, y[1][1]);
        y[1][2] = cmulf(w2, y[1][2]);
        y[1][3] = cmulf(w3, y[1][3]);
        y[2][1] = cmulf(w2, y[2][1]);
        y[2][2] = cmulf(w4, y[2][2]);
        y[2][3] = cmulf(w6, y[2][3]);
        y[3][1] = cmulf(w3, y[3][1]);
        y[3][2] = cmulf(w6, y[3][2]);
        y[3][3] = cmulf(w9, y[3][3]);
        float2 z[16];
#pragma unroll
        for (int k0 = 0; k0 < 4; ++k0)
            dft4(y[0][k0], y[1][k0], y[2][k0], y[3][k0],
                 z[k0], z[4 + k0], z[8 + k0], z[12 + k0]);
        const int q = t & (s - 1);
        const int pw = t - q;
        const int dbase = 16 * t - 15 * q;
        buf[SWZF(dbase)] = z[0];
        if (st == 2) {
#pragma unroll
            for (int j = 1; j < 16; ++j)
                buf[SWZF(dbase + j * s)] = z[j];
        } else {
#pragma unroll
            for (int j = 1; j < 16; ++j)
                buf[SWZF(dbase + j * s)] = cmulf(W[(j * pw) & 4095], z[j]);
        }
    }
    __syncthreads();                     // result visible to caller
}

// ---------------------------------------------------------------------------
// Kernel 2: per f-pair (f0, f0+1) of batch b: load q[b, :, f0:f0+2] directly
// (float2 per s = two-for-one pack), FFT -> unitize -> FFT, emit scaled fp16
// (hi,lo) splits into U2 [b*512+f][s].
// Block remap: p = (id&7)*256 + (id>>3) -> XCD (= id%8) owns one batch, so
// the 8 blocks sharing each 64B q-line are co-resident on one L2.
// ---------------------------------------------------------------------------
__global__ __launch_bounds__(256, 4) void fft_phase_kernel(
        const float* __restrict__ q, H2* __restrict__ u2,
        const float2* __restrict__ W) {
    __shared__ float2 buf[4096];
    const int t = threadIdx.x;
    const int id = blockIdx.x;          // 0..2047
    const int p = (id & 7) * 256 + (id >> 3);
    const int b = p >> 8;
    const int f0 = (p & 255) * 2;
    const float* qb = q + (size_t)b * NS * NF + f0;

#pragma unroll
    for (int i = 0; i < 16; ++i) {
        int s = t + i * 256;
        float2 v = *(const float2*)&qb[(size_t)s * NF];
        buf[SWZF(s)] = v;               // z = q[s,f0] + i*q[s,f0+1]
    }

    fft4096_r16_ip(buf, W, t);          // Z = FFT(x0 + i*x1)

    // Unpack X0, X1; normalize; repack V = U0 + i*U1 (both Hermitian).
    // Each thread owns the pair (k, 4096-k) -> in-place safe.
#pragma unroll
    for (int j = 0; j < 8; ++j) {
        int k = t + j * 256;            // 0..2047
        if (k == 0) {
            float2 z0 = buf[SWZF(0)];
            float2 zh = buf[SWZF(2048)];
            float2 u00 = unitize(make_float2(z0.x, 0.f));
            float2 u10 = unitize(make_float2(z0.y, 0.f));
            buf[SWZF(0)] = make_float2(u00.x, u10.x);
            float2 u0h = unitize(make_float2(zh.x, 0.f));
            float2 u1h = unitize(make_float2(zh.y, 0.f));
            buf[SWZF(2048)] = make_float2(u0h.x, u1h.x);
        } else {
            float2 zk = buf[SWZF(k)];
            float2 zm = buf[SWZF(4096 - k)];
            float2 a = make_float2(0.5f * (zk.x + zm.x), 0.5f * (zk.y - zm.y));
            float2 bq = make_float2(0.5f * (zk.x - zm.x), 0.5f * (zk.y + zm.y));
            float2 x1k = make_float2(bq.y, -bq.x);
            float2 u0 = unitize(a);
            float2 u1 = unitize(x1k);
            buf[SWZF(k)] = make_float2(u0.x - u1.y, u0.y + u1.x);
            buf[SWZF(4096 - k)] = make_float2(u0.x + u1.y, u1.x - u0.y);
        }
    }

    fft4096_r16_ip(buf, W, t);          // F = FFT(V) = u0*N + i*u1*N

    H2* o0 = u2 + (size_t)(2 * p) * NS;
    H2* o1 = o0 + NS;
    const float c = 0.25f;              // (1/4096) * 1024
#pragma unroll
    for (int i = 0; i < 4; ++i) {
        int idx = t + i * 256;
        H2 t0[4], t1[4];
#pragma unroll
        for (int k = 0; k < 4; ++k) {
            float2 e = buf[SWZF(idx * 4 + k)];
            t0[k] = split_h2(e.x * c);
            t1[k] = split_h2(e.y * c);
        }
        *(float4*)&o0[idx * 4] = *(float4*)t0;
        *(float4*)&o1[idx * 4] = *(float4*)t1;
    }
}

// ---------------------------------------------------------------------------
// Kernel 3: A3-builder: U2 [f][s] (H2) -> fragment-major A3.
// elem (row,k) -> halves addr ((row>>4)*32+(k>>5))*512
//                 + ((k>>3)&3)*128 + (row&15)*8 + (k&7); lo at kc+16.
// ---------------------------------------------------------------------------
__global__ __launch_bounds__(256) void abuild_kernel(
        const H2* __restrict__ u2, _Float16* __restrict__ a3) {
    __shared__ H2 tile[64][65];
    const int b = blockIdx.z;
    const int f0 = blockIdx.y * 64;
    const int s0 = blockIdx.x * 64;
    const int t = threadIdx.x;
    const int fr = t >> 6;        // 0..3
    const int sc = t & 63;
#pragma unroll
    for (int i = 0; i < 16; ++i) {
        int f = fr + i * 4;
        tile[f][sc] = u2[(size_t)(b * NF + f0 + f) * NS + s0 + sc];
    }
    __syncthreads();
    const int s = t >> 2;         // 0..63
    const int qd = t & 3;         // f block of 16
    _Float16 xs[16], ys[16];
#pragma unroll
    for (int j = 0; j < 16; ++j) {
        H2 v = tile[qd * 16 + j][s];
        xs[j] = v.x;
        ys[j] = v.y;
    }
    const int f = f0 + qd * 16;           // 16-aligned
    const int s_g = b * NS + s0 + s;
    const int rb = s_g >> 4;
    const int sl = s_g & 15;
    const int kc = f >> 5;
    const int g0 = (f >> 3) & 3;          // in {0, 2}
    size_t base = ((size_t)rb * 32 + kc) * 512;
    *(float4*)(a3 + base + (g0 * 16 + sl) * 8) = ((float4*)xs)[0];
    *(float4*)(a3 + base + ((g0 + 1) * 16 + sl) * 8) = ((float4*)xs)[1];
    base += 16 * 512;                     // lo -> kc + 16
    *(float4*)(a3 + base + (g0 * 16 + sl) * 8) = ((float4*)ys)[0];
    *(float4*)(a3 + base + ((g0 + 1) * 16 + sl) * 8) = ((float4*)ys)[1];
}

// ---------------------------------------------------------------------------
// Kernel 4: B3-builder: items [n][f] f32 -> fragment-major B3.
// ---------------------------------------------------------------------------
__global__ __launch_bounds__(256) void bbuild_kernel(
        const float* __restrict__ items, _Float16* __restrict__ b3) {
    int id = blockIdx.x * 256 + threadIdx.x;   // 1024*128
    int n = id >> 7, fq = id & 127;
    int f = fq * 4;
    float4 v = *(const float4*)&items[(size_t)n * NF + f];
    H2 h0 = split_h2(v.x * 1024.f);
    H2 h1 = split_h2(v.y * 1024.f);
    H2 h2v = split_h2(v.z * 1024.f);
    H2 h3 = split_h2(v.w * 1024.f);
    _Float16 hs[4] = {h0.x, h1.x, h2v.x, h3.x};
    _Float16 ls[4] = {h0.y, h1.y, h2v.y, h3.y};
    const int rb = n >> 4, nl = n & 15;
    const int kc = f >> 5, g = (f >> 3) & 3, off = f & 7;   // off in {0,4}
    size_t base = ((size_t)rb * 32 + kc) * 512 + (g * 16 + nl) * 8 + off;
    *(float2*)(b3 + base) = *(float2*)hs;
    *(float2*)(b3 + base + 16 * 512) = *(float2*)ls;
}

// ---------------------------------------------------------------------------
// Kernel 5: MFMA score GEMM + fused per-(row, n-chunk) argmax. NO LDS staging,
// NO main-loop barriers: fragment-major operands, coalesced 1KB frag loads,
// software-pipelined one chunk ahead in registers.
// Block 128 rows x 128 n, 4 waves (2x2), per-wave 64x64 = 4x4 MFMA frags.
// Per 32-half chunk: 16 frag loads (A/B, hi+lo) + 48 MFMAs.
// Block remap: xcd=id&7, kb innermost per sb -> A-panel L2-resident across
// its 8 uses; B3 (2 MB) L2-hot; each XCD owns 32 sb.
// ---------------------------------------------------------------------------
__global__ __launch_bounds__(256, 2) void gemm_mfma_argmax(
        const _Float16* __restrict__ a3, const _Float16* __restrict__ b3,
        float* __restrict__ pbest, int* __restrict__ pidx) {
    __shared__ float smemf[256];
    __shared__ int smemi[256];
    const int id = blockIdx.x;      // 0..2047
    const int xcd = id & 7;
    const int j = id >> 3;          // 0..255
    const int kb = j & 7;           // innermost on each XCD
    const int sb = xcd * 32 + (j >> 3);
    const int row0 = sb * 128;
    const int n0 = kb * 128;
    const int t = threadIdx.x;
    const int wid = t >> 6, l = t & 63, g = l >> 4, c = l & 15;
    const int wr = wid >> 1, wc = wid & 1;

    floatx4 acc[4][4];
#pragma unroll
    for (int m = 0; m < 4; ++m)
#pragma unroll
        for (int n = 0; n < 4; ++n) acc[m][n] = (floatx4)0.f;

    // frag (m, kc) at pa + m*16384 + kc*512 (halves); hi kc=ch, lo kc=16+ch
    const _Float16* pa = a3 + ((size_t)(sb * 8 + wr * 4) * 32) * 512 + l * 8;
    const _Float16* pb = b3 + ((size_t)(kb * 8 + wc * 4) * 32) * 512 + l * 8;

    half8 cah[4], cal[4], cbh[4], cbl[4];
    half8 nah[4], nal[4], nbh[4], nbl[4];

#define LOADF(ah, al, bh, bl, ch)                                           \
    {                                                                       \
        _Pragma("unroll") for (int m = 0; m < 4; ++m) {                     \
            ah[m] = *(const half8*)(pa + m * 16384 + (ch) * 512);           \
            al[m] = *(const half8*)(pa + m * 16384 + (16 + (ch)) * 512);    \
        }                                                                   \
        _Pragma("unroll") for (int n = 0; n < 4; ++n) {                     \
            bh[n] = *(const half8*)(pb + n * 16384 + (ch) * 512);           \
            bl[n] = *(const half8*)(pb + n * 16384 + (16 + (ch)) * 512);    \
        }                                                                   \
    }

#define MFMAS(ah, al, bh, bl)                                               \
    {                                                                       \
        _Pragma("unroll") for (int m = 0; m < 4; ++m)                       \
        _Pragma("unroll") for (int n = 0; n < 4; ++n) {                     \
            acc[m][n] = __builtin_amdgcn_mfma_f32_16x16x32_f16(             \
                ah[m], bh[n], acc[m][n], 0, 0, 0);                          \
            acc[m][n] = __builtin_amdgcn_mfma_f32_16x16x32_f16(             \
                al[m], bh[n], acc[m][n], 0, 0, 0);                          \
            acc[m][n] = __builtin_amdgcn_mfma_f32_16x16x32_f16(             \
                ah[m], bl[n], acc[m][n], 0, 0, 0);                          \
        }                                                                   \
    }

    LOADF(cah, cal, cbh, cbl, 0);
    for (int c0 = 0; c0 < 16; c0 += 2) {
        if (c0 + 1 < 16) LOADF(nah, nal, nbh, nbl, c0 + 1);
        MFMAS(cah, cal, cbh, cbl);
        if (c0 + 2 < 16) LOADF(cah, cal, cbh, cbl, c0 + 2);
        MFMAS(nah, nal, nbh, nbl);
    }
#undef LOADF
#undef MFMAS

    // argmax: per-thread over 4 n-frags, then across 16-lane row group,
    // then across the 2 wc wave columns via LDS.
#pragma unroll
    for (int m = 0; m < 4; ++m) {
#pragma unroll
        for (int rr = 0; rr < 4; ++rr) {
            float best = acc[m][0][rr];
            int bi = c;                    // n-frag 0, col c
#pragma unroll
            for (int n = 1; n < 4; ++n) {
                float v = acc[m][n][rr];
                int ig = n * 16 + c;
                if (v > best) { best = v; bi = ig; }
            }
#pragma unroll
            for (int off = 1; off < 16; off <<= 1) {
                float ov = __shfl_xor(best, off);
                int oi = __shfl_xor(bi, off);
                if (ov > best || (ov == best && oi < bi)) { best = ov; bi = oi; }
            }
            if (c == 0) {
                int s_local = wr * 64 + m * 16 + 4 * g + rr;
                smemf[wc * 128 + s_local] = best;
                smemi[wc * 128 + s_local] = bi;   // 0..63 within wave n-slice
            }
        }
    }
    __syncthreads();
    if (t < 128) {
        float b0v = smemf[t];
        int b0i = smemi[t];
        float b1v = smemf[128 + t];
        int b1i = smemi[128 + t] + 64;
        float best = b0v; int bi = b0i;
        if (b1v > b0v) { best = b1v; bi = b1i; }   // tie keeps lower (wc=0)
        int row = row0 + t;
        pbest[(size_t)row * NKB + kb] = best;
        pidx[(size_t)row * NKB + kb] = n0 + bi;
    }
}

// ---------------------------------------------------------------------------
// Kernel 6: combine partials (ascending n-chunk, strict >) + SSE vs queries
// ---------------------------------------------------------------------------
__global__ __launch_bounds__(256) void combine_loss_kernel(
        const float* __restrict__ q, const float* __restrict__ items,
        const float* __restrict__ pbest, const int* __restrict__ pidx,
        float* __restrict__ out) {
    const int wid = threadIdx.x >> 6;
    const int lane = threadIdx.x & 63;
    const int row = blockIdx.x * 4 + wid;

    float best = pbest[(size_t)row * NKB];
    int bidx = pidx[(size_t)row * NKB];
#pragma unroll
    for (int g = 1; g < NKB; ++g) {
        float v = pbest[(size_t)row * NKB + g];
        if (v > best) { best = v; bidx = pidx[(size_t)row * NKB + g]; }
    }

    const float4* qr = (const float4*)(q + (size_t)row * NF);
    const float4* mr = (const float4*)(items + (size_t)bidx * NF);
    float sum = 0.f;
#pragma unroll
    for (int i = 0; i < 2; ++i) {
        float4 a = qr[lane + i * 64];
        float4 m = mr[lane + i * 64];
        float dx = a.x - m.x, dy = a.y - m.y, dz = a.z - m.z, dw = a.w - m.w;
        sum += dx * dx + dy * dy + dz * dz + dw * dw;
    }
#pragma unroll
    for (int off = 32; off; off >>= 1) sum += __shfl_down(sum, off, 64);
    if (lane == 0) out[row] = sum;
}

// ---------------------------------------------------------------------------
extern "C" void kernel_launch(void* const* d_in, const int* in_sizes, int n_in,
                              void* d_out, int out_size, void* d_ws, size_t ws_size,
                              hipStream_t stream) {
    const float* q = (const float*)d_in[0];
    const float* items = (const float*)d_in[1];
    float* out = (float*)d_out;

    char* ws = (char*)d_ws;
    // Layout (132.1 MB total):
    //   [0]        W       32 KB
    //   [32K]      A3      64 MB
    //   [32K+64M]  U2      64 MB   (H2 [4096][4096])
    //   [+64M]     B3       2 MB
    //   [+2M]      pbest    1 MB
    //   [+1M]      pidx     1 MB
    float2* W = (float2*)ws;
    _Float16* a3 = (_Float16*)(ws + 32768);
    H2* u2 = (H2*)(ws + 32768 + (size_t)67108864);
    _Float16* b3 = (_Float16*)(ws + 32768 + (size_t)67108864 * 2);
    float* pbest = (float*)(ws + 32768 + (size_t)67108864 * 2 + 2097152);
    int* pidx = (int*)(ws + 32768 + (size_t)67108864 * 2 + 2097152 + 1048576);

    hipLaunchKernelGGL(twiddle_init, dim3(16), dim3(256), 0, stream, W);
    hipLaunchKernelGGL(fft_phase_kernel, dim3(2048), dim3(256), 0, stream,
                       q, u2, W);
    hipLaunchKernelGGL(abuild_kernel, dim3(64, 8, 8), dim3(256), 0, stream,
                       u2, a3);
    hipLaunchKernelGGL(bbuild_kernel, dim3(512), dim3(256), 0, stream,
                       items, b3);
    hipLaunchKernelGGL(gemm_mfma_argmax, dim3(2048), dim3(256), 0, stream,
                       a3, b3, pbest, pidx);
    hipLaunchKernelGGL(combine_loss_kernel, dim3(NROWS / 4), dim3(256), 0,
                       stream, q, items, pbest, pidx, out);
}

// Round 12
// 310.743 us; speedup vs baseline: 1.1952x; 1.1952x over previous
//
#include <hip/hip_runtime.h>

// ---------------------------------------------------------------------------
// GatheringLoss: phase-only FFT reconstruction -> dense score -> top-1 -> SSE
// queries: (8, 4096, 512) f32, items: (1024, 512) f32, out: (8, 4096) f32
// unit = irfft(exp(-1j*angle(rfft(q)))) == real(FFT(X/|X|))/N, X = FFT(q).
// Score GEMM on MFMA f16, exact 2-way split (3 products, lo*lo omitted;
// operands pre-scaled by 2^10 -> argmax invariant).
// A3/B3 fragment-major: a wave's MFMA fragment = one coalesced 1 KB load.
// fft_phase: direct-q two-for-one pack, XCD-remapped blocks, in-place
// single-buffer Stockham (32 KB LDS). NOTE: no min-waves launch_bounds --
// (256,4) forced VGPR 64 and spilled the DFT16 state (+148 MB scratch
// writes, R11 post-mortem); unconstrained = ~108 VGPR, 4 blocks/CU, no spill.
// ---------------------------------------------------------------------------

#define NB 8
#define NS 4096
#define NF 512
#define NK 1024
#define NROWS (NB * NS)      // 32768
#define NKB 8                // n-chunks of 128

// FFT LDS swizzle (verified conflict-reducing for radix-16 Stockham).
#define SWZF(i) ((i) ^ (((i) >> 4) & 15))

typedef _Float16 half8 __attribute__((ext_vector_type(8)));
typedef float floatx4 __attribute__((ext_vector_type(4)));
struct H2 { _Float16 x, y; };   // (hi, lo)

__device__ __forceinline__ float2 cmulf(float2 a, float2 b) {
    return make_float2(a.x * b.x - a.y * b.y, a.x * b.y + a.y * b.x);
}

__device__ __forceinline__ float2 unitize(float2 v) {
    float m2 = v.x * v.x + v.y * v.y;
    if (m2 > 0.f) {
        float inv = 1.0f / sqrtf(m2);
        return make_float2(v.x * inv, v.y * inv);
    }
    return make_float2(1.f, 0.f);
}

__device__ __forceinline__ H2 split_h2(float v) {
    _Float16 h = (_Float16)v;
    float lo = v - (float)h;
    H2 r; r.x = h; r.y = (_Float16)lo; return r;
}

// o[k] = sum_n in[n] * (-i)^(n*k)
__device__ __forceinline__ void dft4(float2 a, float2 b, float2 c, float2 d,
                                     float2& o0, float2& o1, float2& o2, float2& o3) {
    float2 apc = make_float2(a.x + c.x, a.y + c.y);
    float2 amc = make_float2(a.x - c.x, a.y - c.y);
    float2 bpd = make_float2(b.x + d.x, b.y + d.y);
    float2 bmd = make_float2(b.x - d.x, b.y - d.y);
    o0 = make_float2(apc.x + bpd.x, apc.y + bpd.y);
    o1 = make_float2(amc.x + bmd.y, amc.y - bmd.x);   // amc - i*bmd
    o2 = make_float2(apc.x - bpd.x, apc.y - bpd.y);
    o3 = make_float2(amc.x - bmd.y, amc.y + bmd.x);   // amc + i*bmd
}

// ---------------------------------------------------------------------------
// Kernel 1: twiddle table W[k] = exp(-2*pi*i*k/4096), fp64-computed
// ---------------------------------------------------------------------------
__global__ void twiddle_init(float2* __restrict__ W) {
    int k = blockIdx.x * 256 + threadIdx.x;
    double ang = -2.0 * 3.14159265358979323846 * (double)k / 4096.0;
    W[k] = make_float2((float)cos(ang), (float)sin(ang));
}

// ---------------------------------------------------------------------------
// Radix-16 Stockham 4096-pt FFT, IN-PLACE in one LDS buffer: per stage,
// every thread reads its 16 inputs into registers, barrier, computes the
// DFT16, writes, barrier. 3 stages (s = 1, 16, 256), 256 threads.
// ---------------------------------------------------------------------------
__device__ __forceinline__ void fft4096_r16_ip(float2* buf,
                                               const float2* __restrict__ W,
                                               int t) {
    const float C1 = 0.92387953251128674f;   // cos(pi/8)
    const float S1 = 0.38268343236508978f;   // sin(pi/8)
    const float R2 = 0.70710678118654752f;
    const float2 w1 = make_float2(C1, -S1);
    const float2 w2 = make_float2(R2, -R2);
    const float2 w3 = make_float2(S1, -C1);
    const float2 w4 = make_float2(0.f, -1.f);
    const float2 w6 = make_float2(-R2, -R2);
    const float2 w9 = make_float2(-C1, S1);
#pragma unroll
    for (int st = 0; st < 3; ++st) {
        const int s = (st == 0) ? 1 : (st == 1) ? 16 : 256;
        __syncthreads();                 // prior writes visible
        float2 x[16];
#pragma unroll
        for (int j = 0; j < 16; ++j) x[j] = buf[SWZF(t + j * 256)];
        __syncthreads();                 // all reads done before overwrite
        float2 y[4][4];   // y[n0][k0]
#pragma unroll
        for (int n0 = 0; n0 < 4; ++n0)
            dft4(x[n0], x[4 + n0], x[8 + n0], x[12 + n0],
                 y[n0][0], y[n0][1], y[n0][2], y[n0][3]);
        y[1][1] = cmulf(w1, y[1][1]);
        y[1][2] = cmulf(w2, y[1][2]);
        y[1][3] = cmulf(w3, y[1][3]);
        y[2][1] = cmulf(w2, y[2][1]);
        y[2][2] = cmulf(w4, y[2][2]);
        y[2][3] = cmulf(w6, y[2][3]);
        y[3][1] = cmulf(w3, y[3][1]);
        y[3][2] = cmulf(w6, y[3][2]);
        y[3][3] = cmulf(w9, y[3][3]);
        float2 z[16];
#pragma unroll
        for (int k0 = 0; k0 < 4; ++k0)
            dft4(y[0][k0], y[1][k0], y[2][k0], y[3][k0],
                 z[k0], z[4 + k0], z[8 + k0], z[12 + k0]);
        const int q = t & (s - 1);
        const int pw = t - q;
        const int dbase = 16 * t - 15 * q;
        buf[SWZF(dbase)] = z[0];
        if (st == 2) {
#pragma unroll
            for (int j = 1; j < 16; ++j)
                buf[SWZF(dbase + j * s)] = z[j];
        } else {
#pragma unroll
            for (int j = 1; j < 16; ++j)
                buf[SWZF(dbase + j * s)] = cmulf(W[(j * pw) & 4095], z[j]);
        }
    }
    __syncthreads();                     // result visible to caller
}

// ---------------------------------------------------------------------------
// Kernel 2: per f-pair (f0, f0+1) of batch b: load q[b, :, f0:f0+2] directly
// (float2 per s = two-for-one pack), FFT -> unitize -> FFT, emit scaled fp16
// (hi,lo) splits into U2 [b*512+f][s].
// Block remap: p = (id&7)*256 + (id>>3) -> XCD (= id%8) owns one batch, so
// the 8 blocks sharing each 64B q-line are co-resident on one L2.
// ---------------------------------------------------------------------------
__global__ __launch_bounds__(256) void fft_phase_kernel(
        const float* __restrict__ q, H2* __restrict__ u2,
        const float2* __restrict__ W) {
    __shared__ float2 buf[4096];
    const int t = threadIdx.x;
    const int id = blockIdx.x;          // 0..2047
    const int p = (id & 7) * 256 + (id >> 3);
    const int b = p >> 8;
    const int f0 = (p & 255) * 2;
    const float* qb = q + (size_t)b * NS * NF + f0;

#pragma unroll
    for (int i = 0; i < 16; ++i) {
        int s = t + i * 256;
        float2 v = *(const float2*)&qb[(size_t)s * NF];
        buf[SWZF(s)] = v;               // z = q[s,f0] + i*q[s,f0+1]
    }

    fft4096_r16_ip(buf, W, t);          // Z = FFT(x0 + i*x1)

    // Unpack X0, X1; normalize; repack V = U0 + i*U1 (both Hermitian).
    // Each thread owns the pair (k, 4096-k) -> in-place safe.
#pragma unroll
    for (int j = 0; j < 8; ++j) {
        int k = t + j * 256;            // 0..2047
        if (k == 0) {
            float2 z0 = buf[SWZF(0)];
            float2 zh = buf[SWZF(2048)];
            float2 u00 = unitize(make_float2(z0.x, 0.f));
            float2 u10 = unitize(make_float2(z0.y, 0.f));
            buf[SWZF(0)] = make_float2(u00.x, u10.x);
            float2 u0h = unitize(make_float2(zh.x, 0.f));
            float2 u1h = unitize(make_float2(zh.y, 0.f));
            buf[SWZF(2048)] = make_float2(u0h.x, u1h.x);
        } else {
            float2 zk = buf[SWZF(k)];
            float2 zm = buf[SWZF(4096 - k)];
            float2 a = make_float2(0.5f * (zk.x + zm.x), 0.5f * (zk.y - zm.y));
            float2 bq = make_float2(0.5f * (zk.x - zm.x), 0.5f * (zk.y + zm.y));
            float2 x1k = make_float2(bq.y, -bq.x);
            float2 u0 = unitize(a);
            float2 u1 = unitize(x1k);
            buf[SWZF(k)] = make_float2(u0.x - u1.y, u0.y + u1.x);
            buf[SWZF(4096 - k)] = make_float2(u0.x + u1.y, u1.x - u0.y);
        }
    }

    fft4096_r16_ip(buf, W, t);          // F = FFT(V) = u0*N + i*u1*N

    H2* o0 = u2 + (size_t)(2 * p) * NS;
    H2* o1 = o0 + NS;
    const float c = 0.25f;              // (1/4096) * 1024
#pragma unroll
    for (int i = 0; i < 4; ++i) {
        int idx = t + i * 256;
        H2 t0[4], t1[4];
#pragma unroll
        for (int k = 0; k < 4; ++k) {
            float2 e = buf[SWZF(idx * 4 + k)];
            t0[k] = split_h2(e.x * c);
            t1[k] = split_h2(e.y * c);
        }
        *(float4*)&o0[idx * 4] = *(float4*)t0;
        *(float4*)&o1[idx * 4] = *(float4*)t1;
    }
}

// ---------------------------------------------------------------------------
// Kernel 3: A3-builder: U2 [f][s] (H2) -> fragment-major A3.
// elem (row,k) -> halves addr ((row>>4)*32+(k>>5))*512
//                 + ((k>>3)&3)*128 + (row&15)*8 + (k&7); lo at kc+16.
// ---------------------------------------------------------------------------
__global__ __launch_bounds__(256) void abuild_kernel(
        const H2* __restrict__ u2, _Float16* __restrict__ a3) {
    __shared__ H2 tile[64][65];
    const int b = blockIdx.z;
    const int f0 = blockIdx.y * 64;
    const int s0 = blockIdx.x * 64;
    const int t = threadIdx.x;
    const int fr = t >> 6;        // 0..3
    const int sc = t & 63;
#pragma unroll
    for (int i = 0; i < 16; ++i) {
        int f = fr + i * 4;
        tile[f][sc] = u2[(size_t)(b * NF + f0 + f) * NS + s0 + sc];
    }
    __syncthreads();
    const int s = t >> 2;         // 0..63
    const int qd = t & 3;         // f block of 16
    _Float16 xs[16], ys[16];
#pragma unroll
    for (int j = 0; j < 16; ++j) {
        H2 v = tile[qd * 16 + j][s];
        xs[j] = v.x;
        ys[j] = v.y;
    }
    const int f = f0 + qd * 16;           // 16-aligned
    const int s_g = b * NS + s0 + s;
    const int rb = s_g >> 4;
    const int sl = s_g & 15;
    const int kc = f >> 5;
    const int g0 = (f >> 3) & 3;          // in {0, 2}
    size_t base = ((size_t)rb * 32 + kc) * 512;
    *(float4*)(a3 + base + (g0 * 16 + sl) * 8) = ((float4*)xs)[0];
    *(float4*)(a3 + base + ((g0 + 1) * 16 + sl) * 8) = ((float4*)xs)[1];
    base += 16 * 512;                     // lo -> kc + 16
    *(float4*)(a3 + base + (g0 * 16 + sl) * 8) = ((float4*)ys)[0];
    *(float4*)(a3 + base + ((g0 + 1) * 16 + sl) * 8) = ((float4*)ys)[1];
}

// ---------------------------------------------------------------------------
// Kernel 4: B3-builder: items [n][f] f32 -> fragment-major B3.
// ---------------------------------------------------------------------------
__global__ __launch_bounds__(256) void bbuild_kernel(
        const float* __restrict__ items, _Float16* __restrict__ b3) {
    int id = blockIdx.x * 256 + threadIdx.x;   // 1024*128
    int n = id >> 7, fq = id & 127;
    int f = fq * 4;
    float4 v = *(const float4*)&items[(size_t)n * NF + f];
    H2 h0 = split_h2(v.x * 1024.f);
    H2 h1 = split_h2(v.y * 1024.f);
    H2 h2v = split_h2(v.z * 1024.f);
    H2 h3 = split_h2(v.w * 1024.f);
    _Float16 hs[4] = {h0.x, h1.x, h2v.x, h3.x};
    _Float16 ls[4] = {h0.y, h1.y, h2v.y, h3.y};
    const int rb = n >> 4, nl = n & 15;
    const int kc = f >> 5, g = (f >> 3) & 3, off = f & 7;   // off in {0,4}
    size_t base = ((size_t)rb * 32 + kc) * 512 + (g * 16 + nl) * 8 + off;
    *(float2*)(b3 + base) = *(float2*)hs;
    *(float2*)(b3 + base + 16 * 512) = *(float2*)ls;
}

// ---------------------------------------------------------------------------
// Kernel 5: MFMA score GEMM + fused per-(row, n-chunk) argmax. NO LDS staging,
// NO main-loop barriers: fragment-major operands, coalesced 1KB frag loads,
// software-pipelined one chunk ahead in registers.
// Block 128 rows x 128 n, 4 waves (2x2), per-wave 64x64 = 4x4 MFMA frags.
// Per 32-half chunk: 16 frag loads (A/B, hi+lo) + 48 MFMAs.
// Block remap: xcd=id&7, kb innermost per sb -> A-panel L2-resident across
// its 8 uses; B3 (2 MB) L2-hot; each XCD owns 32 sb.
// ---------------------------------------------------------------------------
__global__ __launch_bounds__(256, 2) void gemm_mfma_argmax(
        const _Float16* __restrict__ a3, const _Float16* __restrict__ b3,
        float* __restrict__ pbest, int* __restrict__ pidx) {
    __shared__ float smemf[256];
    __shared__ int smemi[256];
    const int id = blockIdx.x;      // 0..2047
    const int xcd = id & 7;
    const int j = id >> 3;          // 0..255
    const int kb = j & 7;           // innermost on each XCD
    const int sb = xcd * 32 + (j >> 3);
    const int row0 = sb * 128;
    const int n0 = kb * 128;
    const int t = threadIdx.x;
    const int wid = t >> 6, l = t & 63, g = l >> 4, c = l & 15;
    const int wr = wid >> 1, wc = wid & 1;

    floatx4 acc[4][4];
#pragma unroll
    for (int m = 0; m < 4; ++m)
#pragma unroll
        for (int n = 0; n < 4; ++n) acc[m][n] = (floatx4)0.f;

    // frag (m, kc) at pa + m*16384 + kc*512 (halves); hi kc=ch, lo kc=16+ch
    const _Float16* pa = a3 + ((size_t)(sb * 8 + wr * 4) * 32) * 512 + l * 8;
    const _Float16* pb = b3 + ((size_t)(kb * 8 + wc * 4) * 32) * 512 + l * 8;

    half8 cah[4], cal[4], cbh[4], cbl[4];
    half8 nah[4], nal[4], nbh[4], nbl[4];

#define LOADF(ah, al, bh, bl, ch)                                           \
    {                                                                       \
        _Pragma("unroll") for (int m = 0; m < 4; ++m) {                     \
            ah[m] = *(const half8*)(pa + m * 16384 + (ch) * 512);           \
            al[m] = *(const half8*)(pa + m * 16384 + (16 + (ch)) * 512);    \
        }                                                                   \
        _Pragma("unroll") for (int n = 0; n < 4; ++n) {                     \
            bh[n] = *(const half8*)(pb + n * 16384 + (ch) * 512);           \
            bl[n] = *(const half8*)(pb + n * 16384 + (16 + (ch)) * 512);    \
        }                                                                   \
    }

#define MFMAS(ah, al, bh, bl)                                               \
    {                                                                       \
        _Pragma("unroll") for (int m = 0; m < 4; ++m)                       \
        _Pragma("unroll") for (int n = 0; n < 4; ++n) {                     \
            acc[m][n] = __builtin_amdgcn_mfma_f32_16x16x32_f16(             \
                ah[m], bh[n], acc[m][n], 0, 0, 0);                          \
            acc[m][n] = __builtin_amdgcn_mfma_f32_16x16x32_f16(             \
                al[m], bh[n], acc[m][n], 0, 0, 0);                          \
            acc[m][n] = __builtin_amdgcn_mfma_f32_16x16x32_f16(             \
                ah[m], bl[n], acc[m][n], 0, 0, 0);                          \
        }                                                                   \
    }

    LOADF(cah, cal, cbh, cbl, 0);
    for (int c0 = 0; c0 < 16; c0 += 2) {
        if (c0 + 1 < 16) LOADF(nah, nal, nbh, nbl, c0 + 1);
        MFMAS(cah, cal, cbh, cbl);
        if (c0 + 2 < 16) LOADF(cah, cal, cbh, cbl, c0 + 2);
        MFMAS(nah, nal, nbh, nbl);
    }
#undef LOADF
#undef MFMAS

    // argmax: per-thread over 4 n-frags, then across 16-lane row group,
    // then across the 2 wc wave columns via LDS.
#pragma unroll
    for (int m = 0; m < 4; ++m) {
#pragma unroll
        for (int rr = 0; rr < 4; ++rr) {
            float best = acc[m][0][rr];
            int bi = c;                    // n-frag 0, col c
#pragma unroll
            for (int n = 1; n < 4; ++n) {
                float v = acc[m][n][rr];
                int ig = n * 16 + c;
                if (v > best) { best = v; bi = ig; }
            }
#pragma unroll
            for (int off = 1; off < 16; off <<= 1) {
                float ov = __shfl_xor(best, off);
                int oi = __shfl_xor(bi, off);
                if (ov > best || (ov == best && oi < bi)) { best = ov; bi = oi; }
            }
            if (c == 0) {
                int s_local = wr * 64 + m * 16 + 4 * g + rr;
                smemf[wc * 128 + s_local] = best;
                smemi[wc * 128 + s_local] = bi;   // 0..63 within wave n-slice
            }
        }
    }
    __syncthreads();
    if (t < 128) {
        float b0v = smemf[t];
        int b0i = smemi[t];
        float b1v = smemf[128 + t];
        int b1i = smemi[128 + t] + 64;
        float best = b0v; int bi = b0i;
        if (b1v > b0v) { best = b1v; bi = b1i; }   // tie keeps lower (wc=0)
        int row = row0 + t;
        pbest[(size_t)row * NKB + kb] = best;
        pidx[(size_t)row * NKB + kb] = n0 + bi;
    }
}

// ---------------------------------------------------------------------------
// Kernel 6: combine partials (ascending n-chunk, strict >) + SSE vs queries
// ---------------------------------------------------------------------------
__global__ __launch_bounds__(256) void combine_loss_kernel(
        const float* __restrict__ q, const float* __restrict__ items,
        const float* __restrict__ pbest, const int* __restrict__ pidx,
        float* __restrict__ out) {
    const int wid = threadIdx.x >> 6;
    const int lane = threadIdx.x & 63;
    const int row = blockIdx.x * 4 + wid;

    float best = pbest[(size_t)row * NKB];
    int bidx = pidx[(size_t)row * NKB];
#pragma unroll
    for (int g = 1; g < NKB; ++g) {
        float v = pbest[(size_t)row * NKB + g];
        if (v > best) { best = v; bidx = pidx[(size_t)row * NKB + g]; }
    }

    const float4* qr = (const float4*)(q + (size_t)row * NF);
    const float4* mr = (const float4*)(items + (size_t)bidx * NF);
    float sum = 0.f;
#pragma unroll
    for (int i = 0; i < 2; ++i) {
        float4 a = qr[lane + i * 64];
        float4 m = mr[lane + i * 64];
        float dx = a.x - m.x, dy = a.y - m.y, dz = a.z - m.z, dw = a.w - m.w;
        sum += dx * dx + dy * dy + dz * dz + dw * dw;
    }
#pragma unroll
    for (int off = 32; off; off >>= 1) sum += __shfl_down(sum, off, 64);
    if (lane == 0) out[row] = sum;
}

// ---------------------------------------------------------------------------
extern "C" void kernel_launch(void* const* d_in, const int* in_sizes, int n_in,
                              void* d_out, int out_size, void* d_ws, size_t ws_size,
                              hipStream_t stream) {
    const float* q = (const float*)d_in[0];
    const float* items = (const float*)d_in[1];
    float* out = (float*)d_out;

    char* ws = (char*)d_ws;
    // Layout (132.1 MB total):
    //   [0]        W       32 KB
    //   [32K]      A3      64 MB
    //   [32K+64M]  U2      64 MB   (H2 [4096][4096])
    //   [+64M]     B3       2 MB
    //   [+2M]      pbest    1 MB
    //   [+1M]      pidx     1 MB
    float2* W = (float2*)ws;
    _Float16* a3 = (_Float16*)(ws + 32768);
    H2* u2 = (H2*)(ws + 32768 + (size_t)67108864);
    _Float16* b3 = (_Float16*)(ws + 32768 + (size_t)67108864 * 2);
    float* pbest = (float*)(ws + 32768 + (size_t)67108864 * 2 + 2097152);
    int* pidx = (int*)(ws + 32768 + (size_t)67108864 * 2 + 2097152 + 1048576);

    hipLaunchKernelGGL(twiddle_init, dim3(16), dim3(256), 0, stream, W);
    hipLaunchKernelGGL(fft_phase_kernel, dim3(2048), dim3(256), 0, stream,
                       q, u2, W);
    hipLaunchKernelGGL(abuild_kernel, dim3(64, 8, 8), dim3(256), 0, stream,
                       u2, a3);
    hipLaunchKernelGGL(bbuild_kernel, dim3(512), dim3(256), 0, stream,
                       items, b3);
    hipLaunchKernelGGL(gemm_mfma_argmax, dim3(2048), dim3(256), 0, stream,
                       a3, b3, pbest, pidx);
    hipLaunchKernelGGL(combine_loss_kernel, dim3(NROWS / 4), dim3(256), 0,
                       stream, q, items, pbest, pidx, out);
}